// Round 3
// baseline (2614.761 us; speedup 1.0000x reference)
//
#include <hip/hip_runtime.h>
#include <cstdint>
#include <cstddef>

#define TLEN 500
#define BATCH 128
#define NDIM 300
#define EDIM 128
#define CDIM 128
#define UDIM 64
#define FDIM 4
#define G3 384           // 3*E == 3*C
#define CLIPV 5.0f

// ---------------------------------------------------------------------------
// R8 REVERSAL of the prior session's aliasing trick. Counter evidence (R7
// bench): VGPR_Count=116 < 128 VGPRs needed for w0..w31 alone -> weights were
// NOT register-resident. Root cause: non-restrict weight/out pointers mean
// out-stores MAY ALIAS the weights, which makes hoisting the weight loads out
// of the 500-step loop ILLEGAL -> the compiler must re-stream ~196-264 KB/step
// from L1/L2 (~3500 cyc/step, matching the 5670 cyc/step measured vs ~2300
// modeled). Fix:
//  (a) __restrict__ on ALL pointers -> hoisting legal;
//  (b) opaque volatile-asm PIN on each loaded weight value -> a volatile asm
//      result cannot be rematerialized, so the value must stay live in a
//      register for the whole kernel (defeats R5's remat-for-occupancy);
//  (c) amdgpu_waves_per_eu(2,2) keeps the 256-reg/wave budget (ctrl: ~196
//      pinned + ~40 working = ~236; enc: ~128 + ~35 = ~165).
// ---------------------------------------------------------------------------
#define REP32(M) M(0) M(1) M(2) M(3) M(4) M(5) M(6) M(7) \
                 M(8) M(9) M(10) M(11) M(12) M(13) M(14) M(15) \
                 M(16) M(17) M(18) M(19) M(20) M(21) M(22) M(23) \
                 M(24) M(25) M(26) M(27) M(28) M(29) M(30) M(31)
#define REP16(M) M(0) M(1) M(2) M(3) M(4) M(5) M(6) M(7) \
                 M(8) M(9) M(10) M(11) M(12) M(13) M(14) M(15)
#define REP17(M) REP16(M) M(16)

#define DECLW(i) float4 w##i = wsrc[i]; \
    asm volatile("" : "+v"(w##i.x), "+v"(w##i.y), "+v"(w##i.z), "+v"(w##i.w));
#define DECLS(i) float4 s##i = ssrc[i]; \
    asm volatile("" : "+v"(s##i.x), "+v"(s##i.y), "+v"(s##i.z), "+v"(s##i.w));

// broadcast h element j (0..127) from lane registers h0/h1 (readlane needs all
// 64 lanes of the wave live -> only call from wave-uniform control flow)
#define RLH(j) __int_as_float(__builtin_amdgcn_readlane(((j) < 64) ? h0 : h1, (j) & 63))
#define DOTW(i) a0 = fmaf(w##i.x, RLH(4*(i)+0), a0); \
                a1 = fmaf(w##i.y, RLH(4*(i)+1), a1); \
                a2 = fmaf(w##i.z, RLH(4*(i)+2), a2); \
                a3 = fmaf(w##i.w, RLH(4*(i)+3), a3);

// broadcast gen element j (0..63) from lane register gvi
#define RLG(j) __int_as_float(__builtin_amdgcn_readlane(gvi, (j)))
#define DOTS(i) c0 = fmaf(s##i.x, RLG(4*(i)+0), c0); \
                c1 = fmaf(s##i.y, RLG(4*(i)+1), c1); \
                c2 = fmaf(s##i.z, RLG(4*(i)+2), c2); \
                c3 = fmaf(s##i.w, RLG(4*(i)+3), c3);

static __device__ __forceinline__ float sigm(float x) {
    return 1.0f / (1.0f + expf(-x));
}

// ---------------------------------------------------------------------------
// Fused GEMM:  C[m,n] = bias[n] + sum_k A1[m,k]*W[n, wofs1+k]  (K1 terms)
//                               + sum_k A2[m,k]*W[n, wofs2+k]  (K2 terms, A2 may be null)
// A row-major [M,lda], W row-major [N,ldw]. Tile 128x128, BK=8, 256 thr, 8x8 micro.
// (unchanged from R7: double-buffered LDS, 1 barrier/tile, XCD swizzle,
//  float4 epilogue; verified passing)
// ---------------------------------------------------------------------------
__global__ __launch_bounds__(256) void gemm_fused_kernel(
    const float* __restrict__ A1, int lda1, int K1, int wofs1,
    const float* __restrict__ A2, int lda2, int K2, int wofs2,
    const float* __restrict__ Wf, const float* __restrict__ biasf,
    float* __restrict__ Cf,
    const float* __restrict__ Wb, const float* __restrict__ biasb,
    float* __restrict__ Cb,
    int ldw, int ldc, int ndir)
{
    __shared__ float As[2][8][128];
    __shared__ float Bs[2][8][128];
    const int tid = threadIdx.x;

    // ---- XCD-aware bijective work remap (M=64000 -> 500 panels, 3*ndir n-blocks each)
    const int nwg = 1500 * ndir;
    const int d   = blockIdx.x;
    const int xcd = d & 7, blk = d >> 3;
    const int q = nwg >> 3, r = nwg & 7;
    const int work = (xcd < r ? xcd * (q + 1) : r * (q + 1) + (xcd - r) * q) + blk;
    const int npb   = 3 * ndir;
    const int panel = work / npb;
    const int sub   = work - panel * npb;
    const int dir   = (sub >= 3) ? 1 : 0;
    const int nt    = sub - dir * 3;
    const int m0 = panel * 128;
    const int n0 = nt * 128;
    const float* __restrict__ W    = dir ? Wb : Wf;
    const float* __restrict__ bias = dir ? biasb : biasf;
    float* __restrict__ C          = dir ? Cb : Cf;

    const int lr = tid >> 1;           // 0..127 : tile row loaded by this thread
    const int lc = (tid & 1) << 2;     // 0 or 4 : k-offset loaded
    const int ty = tid >> 4;           // 0..15
    const int tx = tid & 15;           // 0..15

    float acc[8][8];
#pragma unroll
    for (int i = 0; i < 8; ++i)
#pragma unroll
        for (int j = 0; j < 8; ++j) acc[i][j] = 0.f;

    int buf = 0;
#pragma unroll 1
    for (int phase = 0; phase < 2; ++phase) {
        const float* __restrict__ A = phase ? A2 : A1;
        if (A == nullptr) continue;
        const int lda  = phase ? lda2  : lda1;
        const int K    = phase ? K2    : K1;
        const int wofs = phase ? wofs2 : wofs1;
        const float* __restrict__ Arow = A + (size_t)(m0 + lr) * lda;
        const float* __restrict__ Wrow = W + (size_t)(n0 + lr) * ldw + wofs;

        // prologue: stage tile 0 into buf.
        {
            float4 av = make_float4(0.f, 0.f, 0.f, 0.f);
            float4 bv = make_float4(0.f, 0.f, 0.f, 0.f);
            if (lc < K) {
                av = *(const float4*)(Arow + lc);
                bv = *(const float4*)(Wrow + lc);
            }
            As[buf][lc + 0][lr] = av.x; As[buf][lc + 1][lr] = av.y;
            As[buf][lc + 2][lr] = av.z; As[buf][lc + 3][lr] = av.w;
            Bs[buf][lc + 0][lr] = bv.x; Bs[buf][lc + 1][lr] = bv.y;
            Bs[buf][lc + 2][lr] = bv.z; Bs[buf][lc + 3][lr] = bv.w;
            __syncthreads();
        }
#pragma unroll 1
        for (int k0 = 0; k0 < K; k0 += 8) {
            const bool more = (k0 + 8 < K);
            // issue next tile's global loads BEFORE the compute (latency cover)
            float4 av = make_float4(0.f, 0.f, 0.f, 0.f);
            float4 bv = make_float4(0.f, 0.f, 0.f, 0.f);
            if (more) {
                const int kn = k0 + 8 + lc;
                if (kn < K) {
                    av = *(const float4*)(Arow + kn);
                    bv = *(const float4*)(Wrow + kn);
                }
            }
            // compute current buffer
            const float (*__restrict__ Asb)[128] = As[buf];
            const float (*__restrict__ Bsb)[128] = Bs[buf];
#pragma unroll
            for (int kk = 0; kk < 8; ++kk) {
                float a[8], bb[8];
#pragma unroll
                for (int i = 0; i < 4; ++i) {
                    a[i]     = Asb[kk][ty * 4 + i];
                    a[4 + i] = Asb[kk][64 + ty * 4 + i];
                }
#pragma unroll
                for (int j = 0; j < 4; ++j) {
                    bb[j]     = Bsb[kk][tx * 4 + j];
                    bb[4 + j] = Bsb[kk][64 + tx * 4 + j];
                }
#pragma unroll
                for (int i = 0; i < 8; ++i)
#pragma unroll
                    for (int j = 0; j < 8; ++j)
                        acc[i][j] = fmaf(a[i], bb[j], acc[i][j]);
            }
            // stage next tile into the alternate buffer
            if (more) {
                float (*__restrict__ Asn)[128] = As[buf ^ 1];
                float (*__restrict__ Bsn)[128] = Bs[buf ^ 1];
                Asn[lc + 0][lr] = av.x; Asn[lc + 1][lr] = av.y;
                Asn[lc + 2][lr] = av.z; Asn[lc + 3][lr] = av.w;
                Bsn[lc + 0][lr] = bv.x; Bsn[lc + 1][lr] = bv.y;
                Bsn[lc + 2][lr] = bv.z; Bsn[lc + 3][lr] = bv.w;
            }
            __syncthreads();           // ONE barrier per tile
            buf ^= (int)more;
        }
    }
    // ---- float4 epilogue: two 4-wide column groups per row ----
    const float4 bias_lo = *(const float4*)(bias + n0 + tx * 4);
    const float4 bias_hi = *(const float4*)(bias + n0 + 64 + tx * 4);
#pragma unroll
    for (int i = 0; i < 8; ++i) {
        const int rr = m0 + ((i < 4) ? (ty * 4 + i) : (64 + ty * 4 + (i - 4)));
        float4 lo = make_float4(acc[i][0] + bias_lo.x, acc[i][1] + bias_lo.y,
                                acc[i][2] + bias_lo.z, acc[i][3] + bias_lo.w);
        float4 hi = make_float4(acc[i][4] + bias_hi.x, acc[i][5] + bias_hi.y,
                                acc[i][6] + bias_hi.z, acc[i][7] + bias_hi.w);
        *(float4*)(C + (size_t)rr * ldc + n0 + tx * 4)      = lo;
        *(float4*)(C + (size_t)rr * ldc + n0 + 64 + tx * 4) = hi;
    }
}

// ---------------------------------------------------------------------------
// Bidirectional encoder GRU scans. 256 WGs (0..127 fwd batch b, 128..255 bwd),
// 384 threads: thread r owns Whh row r in w0..w31 (asm-PINNED VGPR-resident;
// all pointers restrict -> weight-load hoist is legal).
// ---------------------------------------------------------------------------
__attribute__((amdgpu_waves_per_eu(2, 2)))
__global__ __launch_bounds__(384) void enc_scan_kernel(
    const float* __restrict__ xp,      // xp_f, with xp_b at +TLEN*BATCH*G3
    const float* __restrict__ Whh_f, const float* __restrict__ bhh_f,
    const float* __restrict__ Whh_b, const float* __restrict__ bhh_b,
    const float* __restrict__ enc_init,
    float* __restrict__ g)             // [T*B, 2*EDIM]
{
    const int wg  = blockIdx.x;
    const int dir = wg >> 7;
    const int b   = wg & 127;
    const int tid = threadIdx.x;
    const int lane = tid & 63;
    const float* __restrict__ Whh = dir ? Whh_b : Whh_f;
    const float* __restrict__ bhh = dir ? bhh_b : bhh_f;
    const float* __restrict__ xpd = xp + (size_t)dir * ((size_t)TLEN * BATCH * G3);

    __shared__ float h_lds[EDIM];
    __shared__ float hh_lds[G3];

    const float4* wsrc = (const float4*)(Whh + (size_t)tid * 128);
    REP32(DECLW)                       // float4 w0..w31 = this thread's Whh row (pinned)

    const float brow = bhh[tid];
    if (tid < EDIM) h_lds[tid] = enc_init[dir * EDIM + tid];
    __syncthreads();

    for (int s = 0; s < TLEN; ++s) {
        const int t = dir ? (TLEN - 1 - s) : s;
        const size_t row = (size_t)t * BATCH + b;
        // prefetch xp row BEFORE the long dot (consumed after barrier A)
        float xr = 0.f, xz = 0.f, xn = 0.f;
        if (tid < EDIM) {
            const float* __restrict__ xrow = xpd + row * G3;
            xr = xrow[tid]; xz = xrow[EDIM + tid]; xn = xrow[2 * EDIM + tid];
        }
        // unconditional loads + unconditional dot: readlane sees all lanes live
        const int h0 = __float_as_int(h_lds[lane]);
        const int h1 = __float_as_int(h_lds[64 + lane]);
        float a0 = 0.f, a1 = 0.f, a2 = 0.f, a3 = 0.f;
        REP32(DOTW)
        hh_lds[tid] = ((a0 + a1) + (a2 + a3)) + brow;
        __syncthreads();  // A
        if (tid < EDIM) {   // waves 0,1 fully active (wave-uniform branch)
            const float hr = hh_lds[tid], hz = hh_lds[EDIM + tid], hn = hh_lds[2 * EDIM + tid];
            const float r = sigm(xr + hr);
            const float z = sigm(xz + hz);
            const float n = tanhf(xn + r * hn);
            // h_lds[tid]: wave 0 -> h0 (lane==tid), wave 1 -> h1 (64+lane==tid)
            const float hold = (tid < 64) ? __int_as_float(h0) : __int_as_float(h1);
            const float hnew = (1.f - z) * n + z * hold;
            h_lds[tid] = hnew;
            g[row * (2 * EDIM) + dir * EDIM + tid] = fminf(fmaxf(hnew, -CLIPV), CLIPV);
        }
        __syncthreads();  // B
    }
}

// ---------------------------------------------------------------------------
// Controller GRU + latent sample + spike + AR1 calcium. 128 WGs (one per batch),
// 512 threads:
//   tid 0..383  : ctrl_Whh row in w0..w31 ; tid 384..511: W_mu/W_lv row there
//   all threads : W_spk row (clamped) in s0..s16 (only waves 0..4 use it)
// All pointers restrict; weights asm-pinned resident (~236 regs < 256 budget
// from waves_per_eu(2,2)). 4 barriers/step; readlane branches wave-uniform.
// ---------------------------------------------------------------------------
__attribute__((amdgpu_waves_per_eu(2, 2)))
__global__ __launch_bounds__(512) void ctrl_scan_kernel(
    const float* __restrict__ cp,       // [T*B, 384]
    const float* __restrict__ factors,  // [T*B, 4]
    const float* __restrict__ eps,      // [T*B, 64]
    const float* __restrict__ Whh, const float* __restrict__ bhh,
    const float* __restrict__ ctrl_init,
    const float* __restrict__ W_mu, const float* __restrict__ b_mu,
    const float* __restrict__ W_lv, const float* __restrict__ b_lv,
    const float* __restrict__ W_spk, const float* __restrict__ b_spk,
    const float* __restrict__ gain_p, const float* __restrict__ bias_p_p,
    const float* __restrict__ logtau_p,
    float* __restrict__ out)            // [T*B, 300]
{
    const int b   = blockIdx.x;
    const int tid = threadIdx.x;
    const int lane = tid & 63;

    __shared__ float h_lds[CDIM];
    __shared__ float hh_lds[G3];
    __shared__ float lv_lds[UDIM];
    __shared__ float gen_lds[UDIM + FDIM];

    // ---- select this thread's 128-wide weight row, then load into w0..w31 ----
    const float* __restrict__ wptr;
    float bias_row;
    if (tid < G3) {
        wptr = Whh + (size_t)tid * 128;
        bias_row = bhh[tid];
    } else {
        const int mrow = tid - G3;
        if (mrow < UDIM) { wptr = W_mu + (size_t)mrow * 128; bias_row = b_mu[mrow]; }
        else             { wptr = W_lv + (size_t)(mrow - UDIM) * 128; bias_row = b_lv[mrow - UDIM]; }
    }
    const float4* wsrc = (const float4*)wptr;
    REP32(DECLW)                       // float4 w0..w31 (pinned)

    // ---- W_spk row (clamped for pad threads; loaded by ALL threads) ----
    const int srow = (tid < NDIM) ? tid : (NDIM - 1);
    const float4* ssrc = (const float4*)(W_spk + (size_t)srow * 68);
    REP17(DECLS)                       // float4 s0..s16 (pinned; s16 = factor weights)
    const float bspk_r = b_spk[srow];

    const float gain  = gain_p[0];
    const float biasp = bias_p_p[0];
    const float decay = 1.0f - expf(-logtau_p[0]);
    if (tid < CDIM) h_lds[tid] = ctrl_init[tid];
    float cal = 0.0f;
    __syncthreads();

    int h0 = __float_as_int(h_lds[lane]);
    int h1 = __float_as_int(h_lds[64 + lane]);

    for (int t = 0; t < TLEN; ++t) {
        const size_t row = (size_t)t * BATCH + b;
        // ---- prefetch this step's global rows BEFORE the long dot ----
        float cxr = 0.f, cxz = 0.f, cxn = 0.f;   // cp row (gates, after barrier A)
        float epv = 0.f;                          // eps    (gen, after barrier C)
        float fv  = 0.f;                          // factors (LDS write, after A)
        if (tid < CDIM) {
            const float* __restrict__ cpr = cp + row * G3;
            cxr = cpr[tid]; cxz = cpr[CDIM + tid]; cxn = cpr[2 * CDIM + tid];
        }
        if (tid >= G3 && tid < G3 + UDIM) epv = eps[row * UDIM + (tid - G3)];
        if (tid >= 448 && tid < 448 + FDIM) fv = factors[row * FDIM + (tid - 448)];

        // ---- phase A: hh = Whh @ h + bhh (waves 0..5, wave-uniform) ----
        if (tid < G3) {
            float a0 = 0.f, a1 = 0.f, a2 = 0.f, a3 = 0.f;
            REP32(DOTW)
            hh_lds[tid] = ((a0 + a1) + (a2 + a3)) + bias_row;
        }
        __syncthreads();  // A
        // ---- gates (threads 0..127, waves 0,1), clip state ----
        if (tid < CDIM) {
            const float hr = hh_lds[tid], hz = hh_lds[CDIM + tid], hn = hh_lds[2 * CDIM + tid];
            const float r = sigm(cxr + hr);
            const float z = sigm(cxz + hz);
            const float n = tanhf(cxn + r * hn);
            // h_lds[tid]: wave 0 -> h0, wave 1 -> h1
            const float hold = (tid < 64) ? __int_as_float(h0) : __int_as_float(h1);
            float hnew = (1.f - z) * n + z * hold;
            hnew = fminf(fmaxf(hnew, -CLIPV), CLIPV);
            h_lds[tid] = hnew;
        }
        if (tid >= 448 && tid < 448 + FDIM) {
            gen_lds[UDIM + (tid - 448)] = fv;
        }
        __syncthreads();  // B
        h0 = __float_as_int(h_lds[lane]);        // reload new h (all lanes live)
        h1 = __float_as_int(h_lds[64 + lane]);
        // ---- phase B: mu / lv (threads 384..511, waves 6,7, wave-uniform) ----
        float muv = 0.f;
        if (tid >= G3) {
            float a0 = 0.f, a1 = 0.f, a2 = 0.f, a3 = 0.f;
            REP32(DOTW)
            const float v = ((a0 + a1) + (a2 + a3)) + bias_row;
            const int mrow = tid - G3;
            if (mrow < UDIM) muv = v; else lv_lds[mrow - UDIM] = v;
        }
        __syncthreads();  // C
        if (tid >= G3 && tid < G3 + UDIM) {
            const int j = tid - G3;
            gen_lds[j] = muv + expf(0.5f * lv_lds[j]) * epv;
        }
        __syncthreads();  // D
        // ---- phase C: spike + calcium (waves 0..4, WAVE-UNIFORM branch) ----
        if (tid < 320) {
            const int gvi = __float_as_int(gen_lds[lane]);  // all 64 lanes live
            float c0 = 0.f, c1 = 0.f, c2 = 0.f, c3 = 0.f;
            REP16(DOTS)
            float acc = (c0 + c1) + (c2 + c3);
            acc = fmaf(s16.x, gen_lds[UDIM + 0], acc);
            acc = fmaf(s16.y, gen_lds[UDIM + 1], acc);
            acc = fmaf(s16.z, gen_lds[UDIM + 2], acc);
            acc = fmaf(s16.w, gen_lds[UDIM + 3], acc);
            acc += bspk_r;
            const float sp = fmaxf(expf(acc) - 1.0f, 0.0f);
            cal = cal * decay + gain * sp + biasp;
            if (tid < NDIM) out[row * NDIM + tid] = cal;  // only the store diverges
        }
        // no barrier E: phase-C reads precede barrier A of next iter; all
        // conflicting writes next iter occur after that barrier (see R2 proof).
    }
}

// ---------------------------------------------------------------------------
extern "C" void kernel_launch(void* const* d_in, const int* in_sizes, int n_in,
                              void* d_out, int out_size, void* d_ws, size_t ws_size,
                              hipStream_t stream) {
    const float* x         = (const float*)d_in[0];
    const float* factors   = (const float*)d_in[1];
    const float* eps       = (const float*)d_in[2];
    const float* enc_Wih_f = (const float*)d_in[3];
    const float* enc_Whh_f = (const float*)d_in[4];
    const float* enc_bih_f = (const float*)d_in[5];
    const float* enc_bhh_f = (const float*)d_in[6];
    const float* enc_Wih_b = (const float*)d_in[7];
    const float* enc_Whh_b = (const float*)d_in[8];
    const float* enc_bih_b = (const float*)d_in[9];
    const float* enc_bhh_b = (const float*)d_in[10];
    const float* enc_init  = (const float*)d_in[11];
    const float* ctrl_Wih  = (const float*)d_in[12];
    const float* ctrl_Whh  = (const float*)d_in[13];
    const float* ctrl_bih  = (const float*)d_in[14];
    const float* ctrl_bhh  = (const float*)d_in[15];
    const float* ctrl_init = (const float*)d_in[16];
    const float* W_mu      = (const float*)d_in[17];
    const float* b_mu      = (const float*)d_in[18];
    const float* W_lv      = (const float*)d_in[19];
    const float* b_lv      = (const float*)d_in[20];
    const float* W_spk     = (const float*)d_in[21];
    const float* b_spk     = (const float*)d_in[22];
    const float* gain      = (const float*)d_in[23];
    const float* bias_p    = (const float*)d_in[24];
    const float* logtau    = (const float*)d_in[25];
    float* out = (float*)d_out;
    float* ws  = (float*)d_ws;

    const size_t PROJ = (size_t)TLEN * BATCH * G3;   // 24,576,000 floats
    float* xpf = ws;
    float* xpb = ws + PROJ;
    float* g   = ws + 2 * PROJ;                      // [T*B, 256]
    float* cp  = ws;                                 // reuse xpf region after encoder

    // merged encoder projections (ndir=2): xp_f = x@Wf.T+bf ; xp_b = x@Wb.T+bb
    gemm_fused_kernel<<<3000, 256, 0, stream>>>(
        x, NDIM, NDIM, 0,
        nullptr, 0, 0, 0,
        enc_Wih_f, enc_bih_f, xpf,
        enc_Wih_b, enc_bih_b, xpb,
        NDIM, G3, 2);
    // bidirectional encoder scans -> g (clipped)
    enc_scan_kernel<<<256, 384, 0, stream>>>(xpf, enc_Whh_f, enc_bhh_f,
                                             enc_Whh_b, enc_bhh_b, enc_init, g);
    // cp = g @ ctrl_Wih[:, :256].T + x @ ctrl_Wih[:, 256:].T + ctrl_bih
    gemm_fused_kernel<<<1500, 256, 0, stream>>>(
        g, 2 * EDIM, 2 * EDIM, 0,
        x, NDIM, NDIM, 2 * EDIM,
        ctrl_Wih, ctrl_bih, cp,
        nullptr, nullptr, nullptr,
        2 * EDIM + NDIM, G3, 1);
    // controller scan + latent + spike + calcium -> out
    ctrl_scan_kernel<<<128, 512, 0, stream>>>(cp, factors, eps,
                                              ctrl_Whh, ctrl_bhh, ctrl_init,
                                              W_mu, b_mu, W_lv, b_lv,
                                              W_spk, b_spk,
                                              gain, bias_p, logtau, out);
}

// Round 5
// 2286.465 us; speedup vs baseline: 1.1436x; 1.1436x over previous
//
#include <hip/hip_runtime.h>
#include <cstdint>
#include <cstddef>

#define TLEN 500
#define BATCH 128
#define NDIM 300
#define EDIM 128
#define CDIM 128
#define UDIM 64
#define FDIM 4
#define G3 384           // 3*E == 3*C
#define CLIPV 5.0f

// ---------------------------------------------------------------------------
// R9/R10. Register-residency coaxing is DEAD: R7 (alias trick) and R8
// (restrict + volatile-asm pins) produced byte-identical counters (VGPR=116,
// 1178 us) -- the allocator streams weights from L1/L2 either way, and that
// is NOT the bottleneck. Counter arithmetic: 5654 cyc/step vs ~1550 cyc/step
// of pure VALU issue (matches VALUBusy 21.5%) -> ~4000 cyc/step is PHASE
// SERIALIZATION (A -> gates -> B -> u -> C across 4 barriers, most waves
// idle in each phase).
// ctrl_scan: 2-deep software pipeline, 2 barriers/step:
//   seg1: waves0-5: A_i (hh=Whh@h_i)   || waves6,7: mu/lv(h_i) for step i-1
//   seg2: waves0,1: gates_i -> h_{i+1} || wave6: u_{i-1}->gen || waves2-7:
//         spike+calcium+store for step i-2 (gen double-buffered)
// The recurrent chain is only h->hh->gates->h; decoder lags 1-2 steps.
// (R10 = identical resubmit of R9: container failed twice, never executed.
//  Paper audit of index/race/uniformity found no defect.)
// ---------------------------------------------------------------------------
#define REP32(M) M(0) M(1) M(2) M(3) M(4) M(5) M(6) M(7) \
                 M(8) M(9) M(10) M(11) M(12) M(13) M(14) M(15) \
                 M(16) M(17) M(18) M(19) M(20) M(21) M(22) M(23) \
                 M(24) M(25) M(26) M(27) M(28) M(29) M(30) M(31)
#define REP16(M) M(0) M(1) M(2) M(3) M(4) M(5) M(6) M(7) \
                 M(8) M(9) M(10) M(11) M(12) M(13) M(14) M(15)
#define REP17(M) REP16(M) M(16)

#define DECLW(i) float4 w##i = wsrc[i];
#define DECLS(i) float4 s##i = ssrc[i];

// broadcast h element j (0..127) from lane registers h0/h1 (readlane needs all
// 64 lanes of the wave live -> only call from wave-uniform control flow)
#define RLH(j) __int_as_float(__builtin_amdgcn_readlane(((j) < 64) ? h0 : h1, (j) & 63))
#define DOTW(i) a0 = fmaf(w##i.x, RLH(4*(i)+0), a0); \
                a1 = fmaf(w##i.y, RLH(4*(i)+1), a1); \
                a2 = fmaf(w##i.z, RLH(4*(i)+2), a2); \
                a3 = fmaf(w##i.w, RLH(4*(i)+3), a3);

// broadcast gen element j (0..63) from lane register gvi
#define RLG(j) __int_as_float(__builtin_amdgcn_readlane(gvi, (j)))
#define DOTS(i) c0 = fmaf(s##i.x, RLG(4*(i)+0), c0); \
                c1 = fmaf(s##i.y, RLG(4*(i)+1), c1); \
                c2 = fmaf(s##i.z, RLG(4*(i)+2), c2); \
                c3 = fmaf(s##i.w, RLG(4*(i)+3), c3);

static __device__ __forceinline__ float sigm(float x) {
    return 1.0f / (1.0f + expf(-x));
}

// ---------------------------------------------------------------------------
// Fused GEMM (unchanged from R7: verified passing): double-buffered LDS,
// 1 barrier/tile, XCD swizzle, float4 epilogue. Tile 128x128, BK=8, 256 thr.
// ---------------------------------------------------------------------------
__global__ __launch_bounds__(256) void gemm_fused_kernel(
    const float* __restrict__ A1, int lda1, int K1, int wofs1,
    const float* __restrict__ A2, int lda2, int K2, int wofs2,
    const float* __restrict__ Wf, const float* __restrict__ biasf,
    float* __restrict__ Cf,
    const float* __restrict__ Wb, const float* __restrict__ biasb,
    float* __restrict__ Cb,
    int ldw, int ldc, int ndir)
{
    __shared__ float As[2][8][128];
    __shared__ float Bs[2][8][128];
    const int tid = threadIdx.x;

    const int nwg = 1500 * ndir;
    const int d   = blockIdx.x;
    const int xcd = d & 7, blk = d >> 3;
    const int q = nwg >> 3, r = nwg & 7;
    const int work = (xcd < r ? xcd * (q + 1) : r * (q + 1) + (xcd - r) * q) + blk;
    const int npb   = 3 * ndir;
    const int panel = work / npb;
    const int sub   = work - panel * npb;
    const int dir   = (sub >= 3) ? 1 : 0;
    const int nt    = sub - dir * 3;
    const int m0 = panel * 128;
    const int n0 = nt * 128;
    const float* __restrict__ W    = dir ? Wb : Wf;
    const float* __restrict__ bias = dir ? biasb : biasf;
    float* __restrict__ C          = dir ? Cb : Cf;

    const int lr = tid >> 1;
    const int lc = (tid & 1) << 2;
    const int ty = tid >> 4;
    const int tx = tid & 15;

    float acc[8][8];
#pragma unroll
    for (int i = 0; i < 8; ++i)
#pragma unroll
        for (int j = 0; j < 8; ++j) acc[i][j] = 0.f;

    int buf = 0;
#pragma unroll 1
    for (int phase = 0; phase < 2; ++phase) {
        const float* __restrict__ A = phase ? A2 : A1;
        if (A == nullptr) continue;
        const int lda  = phase ? lda2  : lda1;
        const int K    = phase ? K2    : K1;
        const int wofs = phase ? wofs2 : wofs1;
        const float* __restrict__ Arow = A + (size_t)(m0 + lr) * lda;
        const float* __restrict__ Wrow = W + (size_t)(n0 + lr) * ldw + wofs;

        {
            float4 av = make_float4(0.f, 0.f, 0.f, 0.f);
            float4 bv = make_float4(0.f, 0.f, 0.f, 0.f);
            if (lc < K) {
                av = *(const float4*)(Arow + lc);
                bv = *(const float4*)(Wrow + lc);
            }
            As[buf][lc + 0][lr] = av.x; As[buf][lc + 1][lr] = av.y;
            As[buf][lc + 2][lr] = av.z; As[buf][lc + 3][lr] = av.w;
            Bs[buf][lc + 0][lr] = bv.x; Bs[buf][lc + 1][lr] = bv.y;
            Bs[buf][lc + 2][lr] = bv.z; Bs[buf][lc + 3][lr] = bv.w;
            __syncthreads();
        }
#pragma unroll 1
        for (int k0 = 0; k0 < K; k0 += 8) {
            const bool more = (k0 + 8 < K);
            float4 av = make_float4(0.f, 0.f, 0.f, 0.f);
            float4 bv = make_float4(0.f, 0.f, 0.f, 0.f);
            if (more) {
                const int kn = k0 + 8 + lc;
                if (kn < K) {
                    av = *(const float4*)(Arow + kn);
                    bv = *(const float4*)(Wrow + kn);
                }
            }
            const float (*__restrict__ Asb)[128] = As[buf];
            const float (*__restrict__ Bsb)[128] = Bs[buf];
#pragma unroll
            for (int kk = 0; kk < 8; ++kk) {
                float a[8], bb[8];
#pragma unroll
                for (int i = 0; i < 4; ++i) {
                    a[i]     = Asb[kk][ty * 4 + i];
                    a[4 + i] = Asb[kk][64 + ty * 4 + i];
                }
#pragma unroll
                for (int j = 0; j < 4; ++j) {
                    bb[j]     = Bsb[kk][tx * 4 + j];
                    bb[4 + j] = Bsb[kk][64 + tx * 4 + j];
                }
#pragma unroll
                for (int i = 0; i < 8; ++i)
#pragma unroll
                    for (int j = 0; j < 8; ++j)
                        acc[i][j] = fmaf(a[i], bb[j], acc[i][j]);
            }
            if (more) {
                float (*__restrict__ Asn)[128] = As[buf ^ 1];
                float (*__restrict__ Bsn)[128] = Bs[buf ^ 1];
                Asn[lc + 0][lr] = av.x; Asn[lc + 1][lr] = av.y;
                Asn[lc + 2][lr] = av.z; Asn[lc + 3][lr] = av.w;
                Bsn[lc + 0][lr] = bv.x; Bsn[lc + 1][lr] = bv.y;
                Bsn[lc + 2][lr] = bv.z; Bsn[lc + 3][lr] = bv.w;
            }
            __syncthreads();
            buf ^= (int)more;
        }
    }
    const float4 bias_lo = *(const float4*)(bias + n0 + tx * 4);
    const float4 bias_hi = *(const float4*)(bias + n0 + 64 + tx * 4);
#pragma unroll
    for (int i = 0; i < 8; ++i) {
        const int rr = m0 + ((i < 4) ? (ty * 4 + i) : (64 + ty * 4 + (i - 4)));
        float4 lo = make_float4(acc[i][0] + bias_lo.x, acc[i][1] + bias_lo.y,
                                acc[i][2] + bias_lo.z, acc[i][3] + bias_lo.w);
        float4 hi = make_float4(acc[i][4] + bias_hi.x, acc[i][5] + bias_hi.y,
                                acc[i][6] + bias_hi.z, acc[i][7] + bias_hi.w);
        *(float4*)(C + (size_t)rr * ldc + n0 + tx * 4)      = lo;
        *(float4*)(C + (size_t)rr * ldc + n0 + 64 + tx * 4) = hi;
    }
}

// ---------------------------------------------------------------------------
// Bidirectional encoder GRU scans (unchanged structure; restrict everywhere).
// ---------------------------------------------------------------------------
__attribute__((amdgpu_waves_per_eu(2, 2)))
__global__ __launch_bounds__(384) void enc_scan_kernel(
    const float* __restrict__ xp,
    const float* __restrict__ Whh_f, const float* __restrict__ bhh_f,
    const float* __restrict__ Whh_b, const float* __restrict__ bhh_b,
    const float* __restrict__ enc_init,
    float* __restrict__ g)
{
    const int wg  = blockIdx.x;
    const int dir = wg >> 7;
    const int b   = wg & 127;
    const int tid = threadIdx.x;
    const int lane = tid & 63;
    const float* __restrict__ Whh = dir ? Whh_b : Whh_f;
    const float* __restrict__ bhh = dir ? bhh_b : bhh_f;
    const float* __restrict__ xpd = xp + (size_t)dir * ((size_t)TLEN * BATCH * G3);

    __shared__ float h_lds[EDIM];
    __shared__ float hh_lds[G3];

    const float4* wsrc = (const float4*)(Whh + (size_t)tid * 128);
    REP32(DECLW)

    const float brow = bhh[tid];
    if (tid < EDIM) h_lds[tid] = enc_init[dir * EDIM + tid];
    __syncthreads();

    for (int s = 0; s < TLEN; ++s) {
        const int t = dir ? (TLEN - 1 - s) : s;
        const size_t row = (size_t)t * BATCH + b;
        float xr = 0.f, xz = 0.f, xn = 0.f;
        if (tid < EDIM) {
            const float* __restrict__ xrow = xpd + row * G3;
            xr = xrow[tid]; xz = xrow[EDIM + tid]; xn = xrow[2 * EDIM + tid];
        }
        const int h0 = __float_as_int(h_lds[lane]);
        const int h1 = __float_as_int(h_lds[64 + lane]);
        float a0 = 0.f, a1 = 0.f, a2 = 0.f, a3 = 0.f;
        REP32(DOTW)
        hh_lds[tid] = ((a0 + a1) + (a2 + a3)) + brow;
        __syncthreads();  // A
        if (tid < EDIM) {
            const float hr = hh_lds[tid], hz = hh_lds[EDIM + tid], hn = hh_lds[2 * EDIM + tid];
            const float r = sigm(xr + hr);
            const float z = sigm(xz + hz);
            const float n = tanhf(xn + r * hn);
            const float hold = (tid < 64) ? __int_as_float(h0) : __int_as_float(h1);
            const float hnew = (1.f - z) * n + z * hold;
            h_lds[tid] = hnew;
            g[row * (2 * EDIM) + dir * EDIM + tid] = fminf(fmaxf(hnew, -CLIPV), CLIPV);
        }
        __syncthreads();  // B
    }
}

// ---------------------------------------------------------------------------
// ctrl_scan: 2-deep pipelined. 128 WGs (one per batch), 512 threads.
// Thread roles:
//   tid 0..383   (waves 0-5): Whh row `tid` -> A_i in seg1; tid<128 also gates
//   tid 384..447 (wave 6)   : W_mu row (tid-384) -> mu(h_i) for step i-1; u in seg2
//   tid 448..511 (wave 7)   : W_lv row (tid-448) -> lv(h_i) for step i-1
//   tid 128..511 (waves 2-7): W_spk row (tid-128, clamped) -> spike+cal for
//                             step i-2 in seg2 (gen double-buffered)
// Iter range 0..501 (2-iteration drain). 2 barriers/iter. All readlane/dot
// regions under WAVE-UNIFORM guards (i-based or wave-boundary tid ranges).
// ---------------------------------------------------------------------------
__attribute__((amdgpu_waves_per_eu(2, 2)))
__global__ __launch_bounds__(512) void ctrl_scan_kernel(
    const float* __restrict__ cp,       // [T*B, 384]
    const float* __restrict__ factors,  // [T*B, 4]
    const float* __restrict__ eps,      // [T*B, 64]
    const float* __restrict__ Whh, const float* __restrict__ bhh,
    const float* __restrict__ ctrl_init,
    const float* __restrict__ W_mu, const float* __restrict__ b_mu,
    const float* __restrict__ W_lv, const float* __restrict__ b_lv,
    const float* __restrict__ W_spk, const float* __restrict__ b_spk,
    const float* __restrict__ gain_p, const float* __restrict__ bias_p_p,
    const float* __restrict__ logtau_p,
    float* __restrict__ out)            // [T*B, 300]
{
    const int b    = blockIdx.x;
    const int tid  = threadIdx.x;
    const int lane = tid & 63;

    __shared__ float h_lds[CDIM];        // h_i (single buffer: read seg1, write seg2)
    __shared__ float hh_lds[G3];         // A output (write seg1, read seg2)
    __shared__ float lv_lds[UDIM];       // lv (write seg1 wave7, read seg2 wave6)
    __shared__ float gbuf[2][UDIM + FDIM]; // gen double buffer (write seg2 p, read seg2 p^1)

    // ---- per-thread weight row for the seg1 dot ----
    const float* __restrict__ wptr;
    float bias_row;
    if (tid < G3) {
        wptr = Whh + (size_t)tid * 128;
        bias_row = bhh[tid];
    } else if (tid < G3 + UDIM) {
        wptr = W_mu + (size_t)(tid - G3) * 128;
        bias_row = b_mu[tid - G3];
    } else {
        wptr = W_lv + (size_t)(tid - G3 - UDIM) * 128;
        bias_row = b_lv[tid - G3 - UDIM];
    }
    const float4* wsrc = (const float4*)wptr;
    REP32(DECLW)                       // float4 w0..w31

    // ---- W_spk row for spike (threads 128..511 own row tid-128, clamped) ----
    const int r_spk = tid - 128;                       // valid when tid>=128
    const int srow  = (r_spk >= 0 && r_spk < NDIM) ? r_spk : 0;
    const float4* ssrc = (const float4*)(W_spk + (size_t)srow * 68);
    REP17(DECLS)                       // float4 s0..s16 (s16 = factor weights)
    const float bspk_r = b_spk[srow];

    const float gain  = gain_p[0];
    const float biasp = bias_p_p[0];
    const float decay = 1.0f - expf(-logtau_p[0]);
    if (tid < CDIM) h_lds[tid] = ctrl_init[tid];
    float cal = 0.0f;
    float muv = 0.0f;                  // wave-6 register carry across the barrier
    __syncthreads();

    for (int i = 0; i <= TLEN + 1; ++i) {
        const int p = i & 1;
        // ================= SEG 1 =================
        // global prefetches (consumed in seg2; loads only, divergence OK)
        float cxr = 0.f, cxz = 0.f, cxn = 0.f;
        if (i < TLEN && tid < CDIM) {
            const float* __restrict__ cpr = cp + ((size_t)i * BATCH + b) * G3;
            cxr = cpr[tid]; cxz = cpr[CDIM + tid]; cxn = cpr[2 * CDIM + tid];
        }
        float epv = 0.f;
        if (i >= 1 && i <= TLEN && tid >= G3 && tid < G3 + UDIM)
            epv = eps[((size_t)(i - 1) * BATCH + b) * UDIM + (tid - G3)];
        float fv = 0.f;
        if (i >= 1 && i <= TLEN && tid >= G3 + UDIM && tid < G3 + UDIM + FDIM)
            fv = factors[((size_t)(i - 1) * BATCH + b) * FDIM + (tid - G3 - UDIM)];

        int h0 = 0, h1 = 0;
        if (tid < G3) {
            // ---- producers: A_i = Whh @ h_i  (wave-uniform guard: i) ----
            if (i < TLEN) {
                h0 = __float_as_int(h_lds[lane]);
                h1 = __float_as_int(h_lds[64 + lane]);
                float a0 = 0.f, a1 = 0.f, a2 = 0.f, a3 = 0.f;
                REP32(DOTW)
                hh_lds[tid] = ((a0 + a1) + (a2 + a3)) + bias_row;
            }
        } else {
            // ---- consumers: mu/lv(h_i) for decoder step i-1 ----
            if (i >= 1 && i <= TLEN) {
                h0 = __float_as_int(h_lds[lane]);
                h1 = __float_as_int(h_lds[64 + lane]);
                float a0 = 0.f, a1 = 0.f, a2 = 0.f, a3 = 0.f;
                REP32(DOTW)
                const float v = ((a0 + a1) + (a2 + a3)) + bias_row;
                if (tid < G3 + UDIM) muv = v;          // wave 6: mu in register
                else                 lv_lds[lane] = v; // wave 7: lv -> LDS
            }
        }
        __syncthreads();   // S1: hh/lv visible; h_lds reads done
        // ================= SEG 2 =================
        // gates_i -> h_{i+1} (waves 0,1)
        if (i < TLEN && tid < CDIM) {
            const float hr = hh_lds[tid], hz = hh_lds[CDIM + tid], hn = hh_lds[2 * CDIM + tid];
            const float r = sigm(cxr + hr);
            const float z = sigm(cxz + hz);
            const float n = tanhf(cxn + r * hn);
            const float hold = (tid < 64) ? __int_as_float(h0) : __int_as_float(h1);
            float hnew = (1.f - z) * n + z * hold;
            hnew = fminf(fmaxf(hnew, -CLIPV), CLIPV);
            h_lds[tid] = hnew;
        }
        // u_{i-1} -> gen (wave 6) ; factors tail (4 threads of wave 7)
        if (i >= 1 && i <= TLEN) {
            if (tid >= G3 && tid < G3 + UDIM)
                gbuf[p][lane] = muv + expf(0.5f * lv_lds[lane]) * epv;
            else if (tid >= G3 + UDIM && tid < G3 + UDIM + FDIM)
                gbuf[p][UDIM + (tid - G3 - UDIM)] = fv;
        }
        // spike + calcium + store for step i-2 (waves 2-7; uniform guard: i)
        if (i >= 2 && tid >= 128) {
            const int q = p ^ 1;
            const int gvi = __float_as_int(gbuf[q][lane]);  // all 64 lanes live
            float c0 = 0.f, c1 = 0.f, c2 = 0.f, c3 = 0.f;
            REP16(DOTS)
            float acc = (c0 + c1) + (c2 + c3);
            acc = fmaf(s16.x, gbuf[q][UDIM + 0], acc);
            acc = fmaf(s16.y, gbuf[q][UDIM + 1], acc);
            acc = fmaf(s16.z, gbuf[q][UDIM + 2], acc);
            acc = fmaf(s16.w, gbuf[q][UDIM + 3], acc);
            acc += bspk_r;
            const float sp = fmaxf(expf(acc) - 1.0f, 0.0f);
            cal = cal * decay + gain * sp + biasp;
            if (r_spk < NDIM)
                out[((size_t)(i - 2) * BATCH + b) * NDIM + r_spk] = cal;
        }
        __syncthreads();   // S2: h_{i+1}/gen visible for next iter; gbuf[q] reads done
    }
}

// ---------------------------------------------------------------------------
extern "C" void kernel_launch(void* const* d_in, const int* in_sizes, int n_in,
                              void* d_out, int out_size, void* d_ws, size_t ws_size,
                              hipStream_t stream) {
    const float* x         = (const float*)d_in[0];
    const float* factors   = (const float*)d_in[1];
    const float* eps       = (const float*)d_in[2];
    const float* enc_Wih_f = (const float*)d_in[3];
    const float* enc_Whh_f = (const float*)d_in[4];
    const float* enc_bih_f = (const float*)d_in[5];
    const float* enc_bhh_f = (const float*)d_in[6];
    const float* enc_Wih_b = (const float*)d_in[7];
    const float* enc_Whh_b = (const float*)d_in[8];
    const float* enc_bih_b = (const float*)d_in[9];
    const float* enc_bhh_b = (const float*)d_in[10];
    const float* enc_init  = (const float*)d_in[11];
    const float* ctrl_Wih  = (const float*)d_in[12];
    const float* ctrl_Whh  = (const float*)d_in[13];
    const float* ctrl_bih  = (const float*)d_in[14];
    const float* ctrl_bhh  = (const float*)d_in[15];
    const float* ctrl_init = (const float*)d_in[16];
    const float* W_mu      = (const float*)d_in[17];
    const float* b_mu      = (const float*)d_in[18];
    const float* W_lv      = (const float*)d_in[19];
    const float* b_lv      = (const float*)d_in[20];
    const float* W_spk     = (const float*)d_in[21];
    const float* b_spk     = (const float*)d_in[22];
    const float* gain      = (const float*)d_in[23];
    const float* bias_p    = (const float*)d_in[24];
    const float* logtau    = (const float*)d_in[25];
    float* out = (float*)d_out;
    float* ws  = (float*)d_ws;

    const size_t PROJ = (size_t)TLEN * BATCH * G3;   // 24,576,000 floats
    float* xpf = ws;
    float* xpb = ws + PROJ;
    float* g   = ws + 2 * PROJ;                      // [T*B, 256]
    float* cp  = ws;                                 // reuse xpf region after encoder

    // merged encoder projections (ndir=2): xp_f = x@Wf.T+bf ; xp_b = x@Wb.T+bb
    gemm_fused_kernel<<<3000, 256, 0, stream>>>(
        x, NDIM, NDIM, 0,
        nullptr, 0, 0, 0,
        enc_Wih_f, enc_bih_f, xpf,
        enc_Wih_b, enc_bih_b, xpb,
        NDIM, G3, 2);
    // bidirectional encoder scans -> g (clipped)
    enc_scan_kernel<<<256, 384, 0, stream>>>(xpf, enc_Whh_f, enc_bhh_f,
                                             enc_Whh_b, enc_bhh_b, enc_init, g);
    // cp = g @ ctrl_Wih[:, :256].T + x @ ctrl_Wih[:, 256:].T + ctrl_bih
    gemm_fused_kernel<<<1500, 256, 0, stream>>>(
        g, 2 * EDIM, 2 * EDIM, 0,
        x, NDIM, NDIM, 2 * EDIM,
        ctrl_Wih, ctrl_bih, cp,
        nullptr, nullptr, nullptr,
        2 * EDIM + NDIM, G3, 1);
    // controller scan + latent + spike + calcium -> out
    ctrl_scan_kernel<<<128, 512, 0, stream>>>(cp, factors, eps,
                                              ctrl_Whh, ctrl_bhh, ctrl_init,
                                              W_mu, b_mu, W_lv, b_lv,
                                              W_spk, b_spk,
                                              gain, bias_p, logtau, out);
}